// Round 1
// baseline (68.727 us; speedup 1.0000x reference)
//
#include <hip/hip_runtime.h>
#include <math.h>

#define NCLS 20
#define B_N 128
#define A_N 5
#define H_N 26
#define W_N 26
#define HW_N (H_N * W_N)
#define M_N 64
#define CH_N (5 + NCLS)

__device__ __forceinline__ float sigmoidf_(float x) {
    return 1.0f / (1.0f + expf(-x));
}

__device__ __forceinline__ float iou_xywh(float ax, float ay, float aw, float ah,
                                          float bx, float by, float bw, float bh) {
    float tlx = fmaxf(ax - aw * 0.5f, bx - bw * 0.5f);
    float tly = fmaxf(ay - ah * 0.5f, by - bh * 0.5f);
    float brx = fminf(ax + aw * 0.5f, bx + bw * 0.5f);
    float bry = fminf(ay + ah * 0.5f, by + bh * 0.5f);
    float iw = fmaxf(brx - tlx, 0.0f);
    float ih = fmaxf(bry - tly, 0.0f);
    float inter = iw * ih;
    float uni = aw * ah + bw * bh - inter;
    return inter / uni;
}

// Kernel 1: per-(b,m) target prep. Grid: B blocks x M threads (one wave!).
__global__ __launch_bounds__(64) void prep_kernel(
    const float* __restrict__ outputs, const float* __restrict__ targets,
    const float* __restrict__ anchors,
    float* __restrict__ gt, float* __restrict__ delta,
    float* __restrict__ bscale, float* __restrict__ miou,
    int* __restrict__ cellm, int* __restrict__ aim,
    int* __restrict__ gclsm, int* __restrict__ nobj_arr) {
    int b = blockIdx.x;
    int m = threadIdx.x;
    __shared__ float sgt[M_N][4];

    const float* trow = targets + ((size_t)b * M_N + m) * 5;
    float tc = trow[0], tx = trow[1], ty = trow[2], tw = trow[3], th = trow[4];
    float rowsum = tc + tx + ty + tw + th;
    unsigned long long mask = __ballot(rowsum > 0.0f);
    int nobj = __popcll(mask);
    if (m == 0) nobj_arr[b] = nobj;

    float gx = tx * (float)W_N, gy = ty * (float)H_N;
    float gw = tw * (float)W_N, gh = th * (float)H_N;
    sgt[m][0] = gx; sgt[m][1] = gy; sgt[m][2] = gw; sgt[m][3] = gh;
    __syncthreads();

    // cell = clip(floor(gy)*W + floor(gx), 0, HW-1)
    int cell = (int)floorf(gy) * W_N + (int)floorf(gx);
    cell = min(max(cell, 0), HW_N - 1);
    int ccx = cell % W_N, ccy = cell / W_N;

    // anchor argmax (first max wins, like jnp.argmax)
    float best = -1.0f;
    int ai = 0;
    for (int a = 0; a < A_N; ++a) {
        float ov = iou_xywh((float)ccx + 0.5f, (float)ccy + 0.5f,
                            anchors[2 * a], anchors[2 * a + 1],
                            gx, gy, gw, gh);
        if (ov > best) { best = ov; ai = a; }
    }
    float aw = anchors[2 * ai], ah = anchors[2 * ai + 1];
    float d0 = gx - (float)ccx;
    float d1 = gy - (float)ccy;
    float d2 = gw / aw;
    float d3 = gh / ah;

    // decode pred_sel at (b, cell, ai)
    size_t obase = ((size_t)b * (A_N * CH_N) + (size_t)ai * CH_N) * HW_N + cell;
    float o0 = outputs[obase + 0 * HW_N];
    float o1 = outputs[obase + 1 * HW_N];
    float o2 = outputs[obase + 2 * HW_N];
    float o3 = outputs[obase + 3 * HW_N];
    float px = sigmoidf_(o0) + (float)(cell % W_N);
    float py = sigmoidf_(o1) + (float)(cell / W_N);
    float pw = expf(o2) * aw;
    float ph = expf(o3) * ah;
    float bsc = 2.0f - (pw / (float)W_N) * (ph / (float)H_N);

    // miou_sel = max over valid gts of IoU(pred_sel, gt)
    float mi = 0.0f;
    for (int mm = 0; mm < nobj; ++mm) {
        mi = fmaxf(mi, iou_xywh(px, py, pw, ph,
                                sgt[mm][0], sgt[mm][1], sgt[mm][2], sgt[mm][3]));
    }

    size_t gi = (size_t)b * M_N + m;
    gt[gi * 4 + 0] = gx; gt[gi * 4 + 1] = gy;
    gt[gi * 4 + 2] = gw; gt[gi * 4 + 3] = gh;
    delta[gi * 4 + 0] = d0; delta[gi * 4 + 1] = d1;
    delta[gi * 4 + 2] = d2; delta[gi * 4 + 3] = d3;
    bscale[gi] = bsc;
    miou[gi] = mi;
    cellm[gi] = cell;
    aim[gi] = ai;
    gclsm[gi] = (int)tc;
}

// Kernel 2: per-location loss. Grid: B*A blocks x 256 threads; each block owns
// one (b, a) slice and strides hw over HW.
__global__ __launch_bounds__(256) void loss_kernel(
    const float* __restrict__ outputs, const float* __restrict__ anchors,
    const float* __restrict__ gt, const float* __restrict__ delta,
    const float* __restrict__ bscale, const float* __restrict__ miou,
    const int* __restrict__ cellm, const int* __restrict__ aim,
    const int* __restrict__ gclsm, const int* __restrict__ nobj_arr,
    float* __restrict__ gsum, float* __restrict__ Ab, float* __restrict__ Hb,
    unsigned int* __restrict__ haspos) {
    int blk = blockIdx.x;
    int b = blk / A_N;
    int a = blk % A_N;
    int tid = threadIdx.x;

    __shared__ float sgt[M_N][4];
    __shared__ float sdelta[M_N][4];
    __shared__ float sbsc[M_N];
    __shared__ float smiou[M_N];
    __shared__ int scell[M_N];
    __shared__ int sai[M_N];
    __shared__ int scls[M_N];
    __shared__ float redG, redA, redH;
    __shared__ unsigned int redAny;
    __shared__ int snobj;

    if (tid == 0) {
        redG = 0.0f; redA = 0.0f; redH = 0.0f; redAny = 0u;
        snobj = nobj_arr[b];
    }
    if (tid < M_N) {
        size_t gi = (size_t)b * M_N + tid;
        sgt[tid][0] = gt[gi * 4 + 0]; sgt[tid][1] = gt[gi * 4 + 1];
        sgt[tid][2] = gt[gi * 4 + 2]; sgt[tid][3] = gt[gi * 4 + 3];
        sdelta[tid][0] = delta[gi * 4 + 0]; sdelta[tid][1] = delta[gi * 4 + 1];
        sdelta[tid][2] = delta[gi * 4 + 2]; sdelta[tid][3] = delta[gi * 4 + 3];
        sbsc[tid] = bscale[gi];
        smiou[tid] = miou[gi];
        scell[tid] = cellm[gi];
        sai[tid] = aim[gi];
        scls[tid] = gclsm[gi];
    }
    __syncthreads();

    int nobj = snobj;
    float aw = anchors[2 * a], ah = anchors[2 * a + 1];
    size_t obase = ((size_t)b * (A_N * CH_N) + (size_t)a * CH_N) * HW_N;

    float locG = 0.0f, locA = 0.0f, locH = 0.0f;
    unsigned int any = 0u;

    for (int hw = tid; hw < HW_N; hw += 256) {
        float o0 = outputs[obase + 0 * HW_N + hw];
        float o1 = outputs[obase + 1 * HW_N + hw];
        float o2 = outputs[obase + 2 * HW_N + hw];
        float o3 = outputs[obase + 3 * HW_N + hw];
        float o4 = outputs[obase + 4 * HW_N + hw];
        int wx = hw % W_N, wy = hw / W_N;
        float sx = sigmoidf_(o0), sy = sigmoidf_(o1);
        float ew = expf(o2), eh = expf(o3);
        float px = sx + (float)wx, py = sy + (float)wy;
        float pw = ew * aw, ph = eh * ah;

        float maxiou = 0.0f;
        int win = -1;
        for (int m = 0; m < nobj; ++m) {
            maxiou = fmaxf(maxiou, iou_xywh(px, py, pw, ph,
                                            sgt[m][0], sgt[m][1], sgt[m][2], sgt[m][3]));
            if (scell[m] == hw && sai[m] == a) win = m;  // last valid m wins (scan order)
        }
        float conf = sigmoidf_(o4);
        if (maxiou > 0.5f) any = 1u;

        if (win >= 0) {
            // obj loss (im == 2): target = miou_sel
            float dcf = conf - smiou[win];
            locG += dcf * dcf;
            // box loss: bm=1, ((pd - bt) * sqrt(bs))^2 = bs*(pd-bt)^2
            float bs = sbsc[win];
            float e0 = sx - sdelta[win][0];
            float e1 = sy - sdelta[win][1];
            float e2 = ew - sdelta[win][2];
            float e3 = eh - sdelta[win][3];
            locG += bs * (e0 * e0 + e1 * e1 + e2 * e2 + e3 * e3);
            // class CE: lse - logit[cls]
            int cls = scls[win];
            float mx = -1e30f;
            float tv = 0.0f;
            for (int c = 0; c < NCLS; ++c) {
                float v = outputs[obase + (size_t)(5 + c) * HW_N + hw];
                mx = fmaxf(mx, v);
                if (c == cls) tv = v;
            }
            float se = 0.0f;
            for (int c = 0; c < NCLS; ++c) {
                float v = outputs[obase + (size_t)(5 + c) * HW_N + hw];
                se += expf(v - mx);
            }
            locG += (mx + logf(se)) - tv;
        } else if (nobj > 0) {
            // potential noobj (im == 1): conf^2; resolved vs has_pos in finish
            float c2 = conf * conf;
            locA += c2;
            if (maxiou >= 0.5f) locH += c2;
        }
    }

    atomicAdd(&redG, locG);
    atomicAdd(&redA, locA);
    atomicAdd(&redH, locH);
    if (any) atomicOr(&redAny, 1u);
    __syncthreads();
    if (tid == 0) {
        if (redG != 0.0f) atomicAdd(gsum, redG);
        if (redA != 0.0f) atomicAdd(&Ab[b], redA);
        if (redH != 0.0f) atomicAdd(&Hb[b], redH);
        if (redAny) atomicOr(&haspos[b], 1u);
    }
}

// Kernel 3: resolve has_pos and reduce to scalar. 1 block x 64 threads (1 wave).
__global__ __launch_bounds__(64) void finish_kernel(
    const float* __restrict__ gsum, const float* __restrict__ Ab,
    const float* __restrict__ Hb, const unsigned int* __restrict__ haspos,
    const int* __restrict__ nobj_arr, float* __restrict__ out) {
    int t = threadIdx.x;
    float v = 0.0f;
    for (int b = t; b < B_N; b += 64) {
        float noobj = Ab[b] - (haspos[b] ? Hb[b] : 0.0f);
        if (nobj_arr[b] == 0) noobj = 0.0f;
        v += noobj;
    }
    for (int off = 32; off > 0; off >>= 1) v += __shfl_down(v, off);
    if (t == 0) out[0] = (v + gsum[0]) / (float)B_N;
}

extern "C" void kernel_launch(void* const* d_in, const int* in_sizes, int n_in,
                              void* d_out, int out_size, void* d_ws, size_t ws_size,
                              hipStream_t stream) {
    const float* outputs = (const float*)d_in[0];
    const float* targets = (const float*)d_in[1];
    const float* anchors = (const float*)d_in[2];
    float* out = (float*)d_out;

    char* ws = (char*)d_ws;
    size_t off = 0;
    float* gsum = (float*)(ws + off); off += 4;
    unsigned int* haspos = (unsigned int*)(ws + off); off += 4 * B_N;
    float* Ab = (float*)(ws + off); off += 4 * B_N;
    float* Hb = (float*)(ws + off); off += 4 * B_N;
    size_t zero_bytes = off;  // accumulators that must start at 0 every call
    int* nobj = (int*)(ws + off); off += 4 * B_N;
    float* gt = (float*)(ws + off); off += 4 * (size_t)B_N * M_N * 4;
    float* delta = (float*)(ws + off); off += 4 * (size_t)B_N * M_N * 4;
    float* bscale = (float*)(ws + off); off += 4 * (size_t)B_N * M_N;
    float* miou = (float*)(ws + off); off += 4 * (size_t)B_N * M_N;
    int* cellm = (int*)(ws + off); off += 4 * (size_t)B_N * M_N;
    int* aim = (int*)(ws + off); off += 4 * (size_t)B_N * M_N;
    int* gclsm = (int*)(ws + off); off += 4 * (size_t)B_N * M_N;

    hipMemsetAsync(d_ws, 0, zero_bytes, stream);

    prep_kernel<<<B_N, M_N, 0, stream>>>(outputs, targets, anchors,
                                         gt, delta, bscale, miou,
                                         cellm, aim, gclsm, nobj);

    loss_kernel<<<B_N * A_N, 256, 0, stream>>>(outputs, anchors,
                                               gt, delta, bscale, miou,
                                               cellm, aim, gclsm, nobj,
                                               gsum, Ab, Hb, haspos);

    finish_kernel<<<1, 64, 0, stream>>>(gsum, Ab, Hb, haspos, nobj, out);
}

// Round 2
// 38.544 us; speedup vs baseline: 1.7831x; 1.7831x over previous
//
#include <hip/hip_runtime.h>
#include <math.h>

#define NCLS 20
#define B_N 128
#define A_N 5
#define H_N 26
#define W_N 26
#define HW_N (H_N * W_N)
#define M_N 64
#define CH_N (5 + NCLS)

__device__ __forceinline__ float fastrcp(float x) { return __builtin_amdgcn_rcpf(x); }
__device__ __forceinline__ float sigmoidf_(float x) { return fastrcp(1.0f + __expf(-x)); }

__device__ __forceinline__ float iou_div(float ptlx, float ptly, float pbrx, float pbry,
                                         float pa, float4 g, float ga) {
    float ix = fminf(pbrx, g.z) - fmaxf(ptlx, g.x);
    float iy = fminf(pbry, g.w) - fmaxf(ptly, g.y);
    float inter = fmaxf(ix, 0.0f) * fmaxf(iy, 0.0f);
    return inter * fastrcp(pa + ga - inter);
}

// ---------------------------------------------------------------------------
// Kernel 1: per-(b,m) prep + ALL winner loss terms. Grid: B blocks x 64 thr.
// ---------------------------------------------------------------------------
__global__ __launch_bounds__(64) void prep_kernel(
    const float* __restrict__ outputs, const float* __restrict__ targets,
    const float* __restrict__ anchors,
    float4* __restrict__ gt4, float* __restrict__ garea, int* __restrict__ nobj_arr,
    float* __restrict__ gsum, float* __restrict__ Ab, float* __restrict__ Hb) {
    int b = blockIdx.x;
    int m = threadIdx.x;
    __shared__ float4 sg4[M_N];
    __shared__ float sga[M_N];
    __shared__ int skey[M_N];
    __shared__ float sG, sAsub, sHsub;
    if (m == 0) { sG = 0.0f; sAsub = 0.0f; sHsub = 0.0f; }

    const float* trow = targets + ((size_t)b * M_N + m) * 5;
    float tc = trow[0], tx = trow[1], ty = trow[2], tw = trow[3], th = trow[4];
    bool valid = (tc + tx + ty + tw + th) > 0.0f;
    unsigned long long mask = __ballot(valid);
    int nobj = __popcll(mask);
    if (m == 0) nobj_arr[b] = nobj;

    float gx = tx * (float)W_N, gy = ty * (float)H_N;
    float gw = tw * (float)W_N, gh = th * (float)H_N;
    float ga = gw * gh;
    float4 g4 = make_float4(gx - gw * 0.5f, gy - gh * 0.5f,
                            gx + gw * 0.5f, gy + gh * 0.5f);
    sg4[m] = g4; sga[m] = ga;

    // cell + anchor argmax (first max wins)
    int cell = (int)floorf(gy) * W_N + (int)floorf(gx);
    cell = min(max(cell, 0), HW_N - 1);
    int ccx = cell % W_N, ccy = cell / W_N;
    float best = -1.0f;
    int ai = 0;
    float aw = 1.0f, ah = 1.0f;
    for (int a = 0; a < A_N; ++a) {
        float anw = anchors[2 * a], anh = anchors[2 * a + 1];
        float atlx = (float)ccx + 0.5f - anw * 0.5f;
        float atly = (float)ccy + 0.5f - anh * 0.5f;
        float ix = fminf(atlx + anw, g4.z) - fmaxf(atlx, g4.x);
        float iy = fminf(atly + anh, g4.w) - fmaxf(atly, g4.y);
        float inter = fmaxf(ix, 0.0f) * fmaxf(iy, 0.0f);
        float ov = inter * fastrcp(anw * anh + ga - inter);
        if (ov > best) { best = ov; ai = a; aw = anw; ah = anh; }
    }
    skey[m] = valid ? (cell * A_N + ai) : -1;
    __syncthreads();

    gt4[(size_t)b * M_N + m] = g4;
    garea[(size_t)b * M_N + m] = ga;

    // winner: largest valid m with this (cell, anchor) key (lax.scan overwrite)
    bool winner = valid;
    if (valid) {
        int mykey = skey[m];
        for (int mm = m + 1; mm < M_N; ++mm)
            if (skey[mm] == mykey) winner = false;
    }

    if (winner) {
        size_t obase = ((size_t)b * (A_N * CH_N) + (size_t)ai * CH_N) * HW_N + cell;
        float o0 = outputs[obase + 0 * HW_N];
        float o1 = outputs[obase + 1 * HW_N];
        float o2 = outputs[obase + 2 * HW_N];
        float o3 = outputs[obase + 3 * HW_N];
        float o4 = outputs[obase + 4 * HW_N];
        float sx = sigmoidf_(o0), sy = sigmoidf_(o1);
        float ew = __expf(o2), eh = __expf(o3);
        float conf = sigmoidf_(o4);
        float px = sx + (float)ccx, py = sy + (float)ccy;
        float pw = ew * aw, ph = eh * ah;
        float ptlx = px - pw * 0.5f, ptly = py - ph * 0.5f;
        float pbrx = px + pw * 0.5f, pbry = py + ph * 0.5f;
        float pa = pw * ph;

        // miou_sel = max IoU(pred_sel, valid gts)
        float mi = 0.0f;
        for (int mm = 0; mm < nobj; ++mm)
            mi = fmaxf(mi, iou_div(ptlx, ptly, pbrx, pbry, pa, sg4[mm], sga[mm]));

        // obj loss
        float dcf = conf - mi;
        float G = dcf * dcf;
        // box loss: bs * sum((pred_delta - target_delta)^2)
        float bs = 2.0f - (pw / (float)W_N) * (ph / (float)H_N);
        float e0 = sx - (gx - (float)ccx);
        float e1 = sy - (gy - (float)ccy);
        float e2 = ew - gw / aw;
        float e3 = eh - gh / ah;
        G += bs * (e0 * e0 + e1 * e1 + e2 * e2 + e3 * e3);
        // class CE: logsumexp - logit[cls]
        int cls = (int)tc;
        float logits[NCLS];
        float mx = -1e30f;
        #pragma unroll
        for (int c = 0; c < NCLS; ++c) {
            logits[c] = outputs[obase + (size_t)(5 + c) * HW_N];
            mx = fmaxf(mx, logits[c]);
        }
        float se = 0.0f;
        float tv = 0.0f;
        #pragma unroll
        for (int c = 0; c < NCLS; ++c) {
            se += __expf(logits[c] - mx);
            if (c == cls) tv = logits[c];
        }
        G += (mx + __logf(se)) - tv;

        atomicAdd(&sG, G);
        // remove this (winner) location's contribution from the noobj sums
        float c2 = conf * conf;
        atomicAdd(&sAsub, c2);
        if (mi >= 0.5f) atomicAdd(&sHsub, c2);
    }
    __syncthreads();
    if (m == 0) {
        if (sG != 0.0f) atomicAdd(gsum, sG);
        if (sAsub != 0.0f) atomicAdd(&Ab[b], -sAsub);
        if (sHsub != 0.0f) atomicAdd(&Hb[b], -sHsub);
    }
}

// ---------------------------------------------------------------------------
// Kernel 2: noobj-only pass. Grid: (B*A, 3) x 128 thr; 2 locations/thread.
// ---------------------------------------------------------------------------
__global__ __launch_bounds__(128) void noobj_kernel(
    const float* __restrict__ outputs, const float* __restrict__ anchors,
    const float4* __restrict__ gt4, const float* __restrict__ garea,
    const int* __restrict__ nobj_arr,
    float* __restrict__ Ab, float* __restrict__ Hb,
    unsigned int* __restrict__ haspos) {
    int blk = blockIdx.x;
    int b = blk / A_N;
    int a = blk % A_N;
    int tid = threadIdx.x;

    __shared__ float4 sg4[M_N];
    __shared__ float4 sga4[M_N / 4];
    __shared__ int snobj_s;
    __shared__ float rdA[2], rdH[2];
    __shared__ int rdAny[2];

    if (tid == 0) snobj_s = nobj_arr[b];
    if (tid < M_N) {
        sg4[tid] = gt4[(size_t)b * M_N + tid];
        ((float*)sga4)[tid] = garea[(size_t)b * M_N + tid];
    }
    __syncthreads();
    int nobj = snobj_s;
    if (nobj == 0) return;  // uniform: whole batch contributes nothing here

    float aw = anchors[2 * a], ah = anchors[2 * a + 1];
    size_t obase = ((size_t)b * (A_N * CH_N) + (size_t)a * CH_N) * HW_N;

    float locA = 0.0f, locH = 0.0f;
    bool any = false;

    int hw0 = (blockIdx.y * 128 + tid) * 2;
    if (hw0 < HW_N) {
        // W=26 even, hw0 even -> both locations share the row; wx1 = wx0+1
        float2 O0 = *(const float2*)(outputs + obase + 0 * HW_N + hw0);
        float2 O1 = *(const float2*)(outputs + obase + 1 * HW_N + hw0);
        float2 O2 = *(const float2*)(outputs + obase + 2 * HW_N + hw0);
        float2 O3 = *(const float2*)(outputs + obase + 3 * HW_N + hw0);
        float2 O4 = *(const float2*)(outputs + obase + 4 * HW_N + hw0);
        int wx0 = hw0 % W_N, wy0 = hw0 / W_N;

        float sx0 = sigmoidf_(O0.x), sx1 = sigmoidf_(O0.y);
        float sy0 = sigmoidf_(O1.x), sy1 = sigmoidf_(O1.y);
        float pw0 = __expf(O2.x) * aw, pw1 = __expf(O2.y) * aw;
        float ph0 = __expf(O3.x) * ah, ph1 = __expf(O3.y) * ah;
        float px0 = sx0 + (float)wx0, px1 = sx1 + (float)(wx0 + 1);
        float py0 = sy0 + (float)wy0, py1 = sy1 + (float)wy0;

        float ptlx0 = px0 - pw0 * 0.5f, ptly0 = py0 - ph0 * 0.5f;
        float pbrx0 = px0 + pw0 * 0.5f, pbry0 = py0 + ph0 * 0.5f;
        float ptlx1 = px1 - pw1 * 0.5f, ptly1 = py1 - ph1 * 0.5f;
        float pbrx1 = px1 + pw1 * 0.5f, pbry1 = py1 + ph1 * 0.5f;
        float pa0 = pw0 * ph0, pa1 = pw1 * ph1;

        // sign(maxd) answers both (max_iou > 0.5) and (max_iou >= 0.5):
        // iou >= 0.5  <=>  2*inter >= union  <=>  3*inter - (pa+ga) >= 0
        float maxd0 = -1e30f, maxd1 = -1e30f;
        int m4 = nobj & ~3;
        for (int mq = 0; mq < m4; mq += 4) {
            float4 a4 = sga4[mq >> 2];
            float gaArr[4] = {a4.x, a4.y, a4.z, a4.w};
            #pragma unroll
            for (int k = 0; k < 4; ++k) {
                float4 g = sg4[mq + k];
                float s = pa0 + gaArr[k];
                float ix0 = fminf(pbrx0, g.z) - fmaxf(ptlx0, g.x);
                float iy0 = fminf(pbry0, g.w) - fmaxf(ptly0, g.y);
                float in0 = fmaxf(ix0, 0.0f) * fmaxf(iy0, 0.0f);
                maxd0 = fmaxf(maxd0, fmaf(3.0f, in0, -s));
                float s1 = pa1 + gaArr[k];
                float ix1 = fminf(pbrx1, g.z) - fmaxf(ptlx1, g.x);
                float iy1 = fminf(pbry1, g.w) - fmaxf(ptly1, g.y);
                float in1 = fmaxf(ix1, 0.0f) * fmaxf(iy1, 0.0f);
                maxd1 = fmaxf(maxd1, fmaf(3.0f, in1, -s1));
            }
        }
        for (int m = m4; m < nobj; ++m) {
            float4 g = sg4[m];
            float ga_ = ((const float*)sga4)[m];
            float s = pa0 + ga_;
            float ix0 = fminf(pbrx0, g.z) - fmaxf(ptlx0, g.x);
            float iy0 = fminf(pbry0, g.w) - fmaxf(ptly0, g.y);
            float in0 = fmaxf(ix0, 0.0f) * fmaxf(iy0, 0.0f);
            maxd0 = fmaxf(maxd0, fmaf(3.0f, in0, -s));
            float s1 = pa1 + ga_;
            float ix1 = fminf(pbrx1, g.z) - fmaxf(ptlx1, g.x);
            float iy1 = fminf(pbry1, g.w) - fmaxf(ptly1, g.y);
            float in1 = fmaxf(ix1, 0.0f) * fmaxf(iy1, 0.0f);
            maxd1 = fmaxf(maxd1, fmaf(3.0f, in1, -s1));
        }
        float conf0 = sigmoidf_(O4.x), conf1 = sigmoidf_(O4.y);
        float c20 = conf0 * conf0, c21 = conf1 * conf1;
        locA = c20 + c21;
        locH = (maxd0 >= 0.0f ? c20 : 0.0f) + (maxd1 >= 0.0f ? c21 : 0.0f);
        any = (maxd0 > 0.0f) || (maxd1 > 0.0f);
    }

    // reduction: wave shuffle, then cross-wave via LDS, one atomic per block
    int wany = __any(any) ? 1 : 0;
    #pragma unroll
    for (int off = 32; off > 0; off >>= 1) {
        locA += __shfl_down(locA, off);
        locH += __shfl_down(locH, off);
    }
    int wave = tid >> 6, lane = tid & 63;
    if (lane == 0) { rdA[wave] = locA; rdH[wave] = locH; rdAny[wave] = wany; }
    __syncthreads();
    if (tid == 0) {
        float A = rdA[0] + rdA[1];
        float Hs = rdH[0] + rdH[1];
        int anyT = rdAny[0] | rdAny[1];
        if (A != 0.0f) atomicAdd(&Ab[b], A);
        if (Hs != 0.0f) atomicAdd(&Hb[b], Hs);
        if (anyT) atomicOr(&haspos[b], 1u);
    }
}

// ---------------------------------------------------------------------------
// Kernel 3: resolve has_pos, reduce to scalar. 1 block x 64 threads.
// ---------------------------------------------------------------------------
__global__ __launch_bounds__(64) void finish_kernel(
    const float* __restrict__ gsum, const float* __restrict__ Ab,
    const float* __restrict__ Hb, const unsigned int* __restrict__ haspos,
    const int* __restrict__ nobj_arr, float* __restrict__ out) {
    int t = threadIdx.x;
    float v = 0.0f;
    for (int b = t; b < B_N; b += 64) {
        float noobj = Ab[b] - (haspos[b] ? Hb[b] : 0.0f);
        if (nobj_arr[b] == 0) noobj = 0.0f;
        v += noobj;
    }
    #pragma unroll
    for (int off = 32; off > 0; off >>= 1) v += __shfl_down(v, off);
    if (t == 0) out[0] = (v + gsum[0]) / (float)B_N;
}

extern "C" void kernel_launch(void* const* d_in, const int* in_sizes, int n_in,
                              void* d_out, int out_size, void* d_ws, size_t ws_size,
                              hipStream_t stream) {
    const float* outputs = (const float*)d_in[0];
    const float* targets = (const float*)d_in[1];
    const float* anchors = (const float*)d_in[2];
    float* out = (float*)d_out;

    char* ws = (char*)d_ws;
    size_t off = 0;
    float* gsum = (float*)(ws + off); off += 4;
    unsigned int* haspos = (unsigned int*)(ws + off); off += 4 * B_N;
    float* Ab = (float*)(ws + off); off += 4 * B_N;
    float* Hb = (float*)(ws + off); off += 4 * B_N;
    size_t zero_bytes = off;  // accumulators: must start at 0 each call
    int* nobj = (int*)(ws + off); off += 4 * B_N;
    off = (off + 15) & ~(size_t)15;
    float4* gt4 = (float4*)(ws + off); off += 16 * (size_t)B_N * M_N;
    float* garea = (float*)(ws + off); off += 4 * (size_t)B_N * M_N;

    hipMemsetAsync(d_ws, 0, zero_bytes, stream);

    prep_kernel<<<B_N, M_N, 0, stream>>>(outputs, targets, anchors,
                                         gt4, garea, nobj, gsum, Ab, Hb);

    noobj_kernel<<<dim3(B_N * A_N, 3), 128, 0, stream>>>(outputs, anchors,
                                                         gt4, garea, nobj,
                                                         Ab, Hb, haspos);

    finish_kernel<<<1, 64, 0, stream>>>(gsum, Ab, Hb, haspos, nobj, out);
}

// Round 3
// 28.213 us; speedup vs baseline: 2.4360x; 1.3662x over previous
//
#include <hip/hip_runtime.h>
#include <math.h>

#define NCLS 20
#define B_N 128
#define A_N 5
#define H_N 26
#define W_N 26
#define HW_N (H_N * W_N)          // 676
#define M_N 64
#define CH_N (5 + NCLS)           // 25
#define LOCS_PT 4
#define ACT_T (HW_N / LOCS_PT)    // 169 active threads per plane
#define BLK_T 192                 // 3 waves

__device__ __forceinline__ float fastrcp(float x) { return __builtin_amdgcn_rcpf(x); }
__device__ __forceinline__ float sigmoidf_(float x) { return fastrcp(1.0f + __expf(-x)); }

// ---------------------------------------------------------------------------
// Main kernel. Grid: B_N winner blocks first, then B_N*A_N noobj blocks.
// Winner block b: computes all winner (obj/box/class) loss terms -> Gb[b],
//   plus the winner-location conf^2 corrections -> Asub[b], Hsub[b], nobj[b].
// Noobj block (b,a): 4 locs/thread over one 676-loc plane; partial sums ->
//   A_part/H_part/any_part[b*A_N+a]. All outputs written unconditionally.
// ---------------------------------------------------------------------------
__global__ __launch_bounds__(BLK_T) void main_kernel(
    const float* __restrict__ outputs, const float* __restrict__ targets,
    const float* __restrict__ anchors,
    float* __restrict__ A_part, float* __restrict__ H_part,
    int* __restrict__ any_part,
    float* __restrict__ Gb, float* __restrict__ Asub, float* __restrict__ Hsub,
    int* __restrict__ nobjArr) {
    int blk = blockIdx.x;
    bool winnerBlk = (blk < B_N);
    int b = winnerBlk ? blk : ((blk - B_N) / A_N);
    int a = winnerBlk ? 0 : ((blk - B_N) % A_N);
    int tid = threadIdx.x;

    __shared__ float4 sg4[M_N];     // gt tl/br
    __shared__ float sga[M_N];      // gt area
    __shared__ float sgx[M_N], sgy[M_N], sgw[M_N], sgh[M_N], sc[M_N];
    __shared__ int skey[M_N];
    __shared__ int snobj;
    __shared__ float sG, sAsub, sHsub;
    __shared__ float rA[3], rH[3];
    __shared__ int rAny[3];

    if (tid == 0) { sG = 0.0f; sAsub = 0.0f; sHsub = 0.0f; }

    if (tid < M_N) {  // exactly wave 0
        const float* trow = targets + ((size_t)b * M_N + tid) * 5;
        float tc = trow[0], tx = trow[1], ty = trow[2], tw = trow[3], th = trow[4];
        bool valid = (tc + tx + ty + tw + th) > 0.0f;
        unsigned long long mask = __ballot(valid);
        if (tid == 0) snobj = __popcll(mask);
        float gx = tx * (float)W_N, gy = ty * (float)H_N;
        float gw = tw * (float)W_N, gh = th * (float)H_N;
        sg4[tid] = make_float4(gx - gw * 0.5f, gy - gh * 0.5f,
                               gx + gw * 0.5f, gy + gh * 0.5f);
        sga[tid] = gw * gh;
        sgx[tid] = gx; sgy[tid] = gy; sgw[tid] = gw; sgh[tid] = gh; sc[tid] = tc;
    }
    __syncthreads();
    int nobj = snobj;

    if (winnerBlk) {
        // ---- winner (positive-sample) path: one thread per target m ----
        int m = tid;
        bool valid = (tid < M_N) && (m < nobj);  // valid rows are exactly [0,nobj)
        int cell = 0, ai = 0, ccx = 0, ccy = 0;
        float aw = 1.0f, ah = 1.0f;
        if (tid < M_N) {
            float gx = sgx[m], gy = sgy[m];
            float4 g4 = sg4[m];
            float ga = sga[m];
            cell = (int)floorf(gy) * W_N + (int)floorf(gx);
            cell = min(max(cell, 0), HW_N - 1);
            ccx = cell % W_N; ccy = cell / W_N;
            float best = -1.0f;
            #pragma unroll
            for (int aa = 0; aa < A_N; ++aa) {
                float anw = anchors[2 * aa], anh = anchors[2 * aa + 1];
                float atlx = (float)ccx + 0.5f - anw * 0.5f;
                float atly = (float)ccy + 0.5f - anh * 0.5f;
                float ix = fminf(atlx + anw, g4.z) - fmaxf(atlx, g4.x);
                float iy = fminf(atly + anh, g4.w) - fmaxf(atly, g4.y);
                float inter = fmaxf(ix, 0.0f) * fmaxf(iy, 0.0f);
                float ov = inter * fastrcp(anw * anh + ga - inter);
                if (ov > best) { best = ov; ai = aa; aw = anw; ah = anh; }
            }
            skey[m] = valid ? (cell * A_N + ai) : -1;
        }
        __syncthreads();

        // winner = last valid m holding its (cell,anchor) key (lax.scan overwrite)
        bool winner = valid;
        if (valid) {
            int mykey = skey[m];
            for (int mm = m + 1; mm < M_N; ++mm)
                if (skey[mm] == mykey) winner = false;
        }

        if (winner) {
            size_t obase = ((size_t)b * (A_N * CH_N) + (size_t)ai * CH_N) * HW_N + cell;
            float o0 = outputs[obase + 0 * HW_N];
            float o1 = outputs[obase + 1 * HW_N];
            float o2 = outputs[obase + 2 * HW_N];
            float o3 = outputs[obase + 3 * HW_N];
            float o4 = outputs[obase + 4 * HW_N];
            float sx = sigmoidf_(o0), sy = sigmoidf_(o1);
            float ew = __expf(o2), eh = __expf(o3);
            float conf = sigmoidf_(o4);
            float px = sx + (float)ccx, py = sy + (float)ccy;
            float pw = ew * aw, ph = eh * ah;
            float ptlx = px - pw * 0.5f, ptly = py - ph * 0.5f;
            float pbrx = px + pw * 0.5f, pbry = py + ph * 0.5f;
            float pa = pw * ph;

            float mi = 0.0f;
            for (int mm = 0; mm < nobj; ++mm) {
                float4 g = sg4[mm];
                float ix = fminf(pbrx, g.z) - fmaxf(ptlx, g.x);
                float iy = fminf(pbry, g.w) - fmaxf(ptly, g.y);
                float inter = fmaxf(ix, 0.0f) * fmaxf(iy, 0.0f);
                mi = fmaxf(mi, inter * fastrcp(pa + sga[mm] - inter));
            }

            float dcf = conf - mi;
            float G = dcf * dcf;
            float bs = 2.0f - (pw / (float)W_N) * (ph / (float)H_N);
            float e0 = sx - (sgx[m] - (float)ccx);
            float e1 = sy - (sgy[m] - (float)ccy);
            float e2 = ew - sgw[m] / aw;
            float e3 = eh - sgh[m] / ah;
            G += bs * (e0 * e0 + e1 * e1 + e2 * e2 + e3 * e3);

            int cls = (int)sc[m];
            float mx = -1e30f, tv = 0.0f, logits[NCLS];
            #pragma unroll
            for (int c = 0; c < NCLS; ++c) {
                logits[c] = outputs[obase + (size_t)(5 + c) * HW_N];
                mx = fmaxf(mx, logits[c]);
            }
            float se = 0.0f;
            #pragma unroll
            for (int c = 0; c < NCLS; ++c) {
                se += __expf(logits[c] - mx);
                if (c == cls) tv = logits[c];
            }
            G += (mx + __logf(se)) - tv;

            atomicAdd(&sG, G);
            float c2 = conf * conf;
            atomicAdd(&sAsub, c2);
            if (mi >= 0.5f) atomicAdd(&sHsub, c2);
        }
        __syncthreads();
        if (tid == 0) {
            Gb[b] = sG; Asub[b] = sAsub; Hsub[b] = sHsub; nobjArr[b] = nobj;
        }
    } else {
        // ---- noobj path: 4 consecutive locations per thread, float4 loads ----
        float locA = 0.0f, locH = 0.0f;
        bool any = false;
        if (tid < ACT_T) {
            int hw0 = tid * LOCS_PT;
            size_t obase = ((size_t)b * (A_N * CH_N) + (size_t)a * CH_N) * HW_N;
            float4 O0 = *(const float4*)(outputs + obase + 0 * HW_N + hw0);
            float4 O1 = *(const float4*)(outputs + obase + 1 * HW_N + hw0);
            float4 O2 = *(const float4*)(outputs + obase + 2 * HW_N + hw0);
            float4 O3 = *(const float4*)(outputs + obase + 3 * HW_N + hw0);
            float4 O4 = *(const float4*)(outputs + obase + 4 * HW_N + hw0);
            float aw = anchors[2 * a], ah = anchors[2 * a + 1];

            float o0a[4] = {O0.x, O0.y, O0.z, O0.w};
            float o1a[4] = {O1.x, O1.y, O1.z, O1.w};
            float o2a[4] = {O2.x, O2.y, O2.z, O2.w};
            float o3a[4] = {O3.x, O3.y, O3.z, O3.w};

            int wy0 = hw0 / W_N;
            int wx0 = hw0 - wy0 * W_N;

            float ptlx[4], ptly[4], pbrx[4], pbry[4], pa[4], maxd[4];
            int wx = wx0, wy = wy0;
            #pragma unroll
            for (int k = 0; k < 4; ++k) {
                float sx = sigmoidf_(o0a[k]), sy = sigmoidf_(o1a[k]);
                float pw = __expf(o2a[k]) * aw, ph = __expf(o3a[k]) * ah;
                float px = sx + (float)wx, py = sy + (float)wy;
                ptlx[k] = px - pw * 0.5f; ptly[k] = py - ph * 0.5f;
                pbrx[k] = px + pw * 0.5f; pbry[k] = py + ph * 0.5f;
                pa[k] = pw * ph;
                maxd[k] = -1e30f;
                ++wx; if (wx == W_N) { wx = 0; ++wy; }
            }

            // sign of maxd answers iou vs 0.5: iou>=0.5 <=> 3*inter-(pa+ga)>=0
            for (int m = 0; m < nobj; ++m) {
                float4 g = sg4[m];
                float ga = sga[m];
                #pragma unroll
                for (int k = 0; k < 4; ++k) {
                    float ix = fminf(pbrx[k], g.z) - fmaxf(ptlx[k], g.x);
                    float iy = fminf(pbry[k], g.w) - fmaxf(ptly[k], g.y);
                    float in = fmaxf(ix, 0.0f) * fmaxf(iy, 0.0f);
                    maxd[k] = fmaxf(maxd[k], fmaf(3.0f, in, -(pa[k] + ga)));
                }
            }

            float o4a[4] = {O4.x, O4.y, O4.z, O4.w};
            #pragma unroll
            for (int k = 0; k < 4; ++k) {
                float conf = sigmoidf_(o4a[k]);
                float c2 = conf * conf;
                locA += c2;
                locH += (maxd[k] >= 0.0f) ? c2 : 0.0f;
                any = any || (maxd[k] > 0.0f);
            }
        }

        int wany = __any(any) ? 1 : 0;
        #pragma unroll
        for (int off = 32; off > 0; off >>= 1) {
            locA += __shfl_down(locA, off);
            locH += __shfl_down(locH, off);
        }
        int wave = tid >> 6, lane = tid & 63;
        if (lane == 0) { rA[wave] = locA; rH[wave] = locH; rAny[wave] = wany; }
        __syncthreads();
        if (tid == 0) {
            int slot = blk - B_N;
            A_part[slot] = rA[0] + rA[1] + rA[2];
            H_part[slot] = rH[0] + rH[1] + rH[2];
            any_part[slot] = rAny[0] | rAny[1] | rAny[2];
        }
    }
}

// ---------------------------------------------------------------------------
// Finish: 128 threads, one per batch; deterministic fixed-order reduction.
// ---------------------------------------------------------------------------
__global__ __launch_bounds__(128) void finish_kernel(
    const float* __restrict__ A_part, const float* __restrict__ H_part,
    const int* __restrict__ any_part,
    const float* __restrict__ Gb, const float* __restrict__ Asub,
    const float* __restrict__ Hsub, const int* __restrict__ nobjArr,
    float* __restrict__ out) {
    int t = threadIdx.x;  // == b
    float A = -Asub[t], Hs = -Hsub[t];
    int any = 0;
    #pragma unroll
    for (int j = 0; j < A_N; ++j) {
        A += A_part[t * A_N + j];
        Hs += H_part[t * A_N + j];
        any |= any_part[t * A_N + j];
    }
    float noobj = (nobjArr[t] > 0) ? (A - (any ? Hs : 0.0f)) : 0.0f;
    float v = Gb[t] + noobj;
    #pragma unroll
    for (int off = 32; off > 0; off >>= 1) v += __shfl_down(v, off);
    __shared__ float r[2];
    if ((t & 63) == 0) r[t >> 6] = v;
    __syncthreads();
    if (t == 0) out[0] = (r[0] + r[1]) / (float)B_N;
}

extern "C" void kernel_launch(void* const* d_in, const int* in_sizes, int n_in,
                              void* d_out, int out_size, void* d_ws, size_t ws_size,
                              hipStream_t stream) {
    const float* outputs = (const float*)d_in[0];
    const float* targets = (const float*)d_in[1];
    const float* anchors = (const float*)d_in[2];
    float* out = (float*)d_out;

    char* ws = (char*)d_ws;
    size_t off = 0;
    float* A_part = (float*)(ws + off); off += 4 * (size_t)B_N * A_N;
    float* H_part = (float*)(ws + off); off += 4 * (size_t)B_N * A_N;
    int* any_part = (int*)(ws + off);   off += 4 * (size_t)B_N * A_N;
    float* Gb = (float*)(ws + off);     off += 4 * B_N;
    float* Asub = (float*)(ws + off);   off += 4 * B_N;
    float* Hsub = (float*)(ws + off);   off += 4 * B_N;
    int* nobjArr = (int*)(ws + off);    off += 4 * B_N;
    // every slot above is unconditionally written each call -> no memset needed

    main_kernel<<<B_N + B_N * A_N, BLK_T, 0, stream>>>(
        outputs, targets, anchors,
        A_part, H_part, any_part, Gb, Asub, Hsub, nobjArr);

    finish_kernel<<<1, 128, 0, stream>>>(A_part, H_part, any_part,
                                         Gb, Asub, Hsub, nobjArr, out);
}

// Round 4
// 19.329 us; speedup vs baseline: 3.5556x; 1.4596x over previous
//
#include <hip/hip_runtime.h>
#include <math.h>

#define NCLS 20
#define B_N 128
#define A_N 5
#define H_N 26
#define W_N 26
#define HW_N (H_N * W_N)          // 676
#define M_N 64
#define CH_N (5 + NCLS)           // 25
#define HALF_LOC (HW_N / 2)       // 338 locations per half-plane
#define HALF_T (HALF_LOC / 2)     // 169 active threads (2 locs each)
#define BLK_T 192                 // 3 waves
#define WIN_BLKS B_N              // 128 winner blocks (first)
#define NOOBJ_BLKS (B_N * A_N * 2)// 1280 half-plane blocks
#define PARTS_PER_B (A_N * 2)     // 10 partial slots per batch

__device__ __forceinline__ float fastrcp(float x) { return __builtin_amdgcn_rcpf(x); }
__device__ __forceinline__ float sigmoidf_(float x) { return fastrcp(1.0f + __expf(-x)); }

// ---------------------------------------------------------------------------
// Main kernel. Grid: 128 winner blocks, then 1280 noobj half-plane blocks.
// All partial outputs written unconditionally once -> no memset, deterministic.
// ---------------------------------------------------------------------------
__global__ __launch_bounds__(BLK_T) void main_kernel(
    const float* __restrict__ outputs, const float* __restrict__ targets,
    const float* __restrict__ anchors,
    float* __restrict__ A_part, float* __restrict__ H_part,
    int* __restrict__ any_part,
    float* __restrict__ Gb, float* __restrict__ Asub, float* __restrict__ Hsub,
    int* __restrict__ nobjArr) {
    int blk = blockIdx.x;
    bool winnerBlk = (blk < WIN_BLKS);
    int nb = blk - WIN_BLKS;                    // noobj block index
    int plane = nb >> 1;
    int half = nb & 1;
    int b = winnerBlk ? blk : (plane / A_N);
    int a = winnerBlk ? 0 : (plane % A_N);
    int tid = threadIdx.x;

    __shared__ float4 sg4[M_N];                 // gt tl/br
    __shared__ float sgx[M_N], sgy[M_N], sgw[M_N], sgh[M_N], sc[M_N];
    __shared__ int skey[M_N];
    __shared__ int snobj;
    __shared__ float rA[3], rH[3];
    __shared__ int rAny[3];

    // ---- staging: wave 0 builds gt boxes in LDS ----
    if (tid < M_N) {
        const float* trow = targets + ((size_t)b * M_N + tid) * 5;
        float tc = trow[0], tx = trow[1], ty = trow[2], tw = trow[3], th = trow[4];
        bool valid = (tc + tx + ty + tw + th) > 0.0f;
        unsigned long long mask = __ballot(valid);
        if (tid == 0) snobj = __popcll(mask);
        float gx = tx * (float)W_N, gy = ty * (float)H_N;
        float gw = tw * (float)W_N, gh = th * (float)H_N;
        sg4[tid] = make_float4(gx - gw * 0.5f, gy - gh * 0.5f,
                               gx + gw * 0.5f, gy + gh * 0.5f);
        sgx[tid] = gx; sgy[tid] = gy; sgw[tid] = gw; sgh[tid] = gh; sc[tid] = tc;
    }
    __syncthreads();
    int nobj = snobj;

    if (winnerBlk) {
        // ---- winner path: one thread per target m (wave 0 only) ----
        float G = 0.0f, c2A = 0.0f, c2H = 0.0f;
        if (tid < M_N) {
            int m = tid;
            bool valid = (m < nobj);            // valid rows are exactly [0,nobj)
            float gx = sgx[m], gy = sgy[m];
            float4 g4 = sg4[m];
            float ga = sgw[m] * sgh[m];
            int cell = (int)floorf(gy) * W_N + (int)floorf(gx);
            cell = min(max(cell, 0), HW_N - 1);
            int ccx = cell % W_N, ccy = cell / W_N;
            float best = -1.0f;
            int ai = 0; float aw = 1.0f, ah = 1.0f;
            #pragma unroll
            for (int aa = 0; aa < A_N; ++aa) {
                float anw = anchors[2 * aa], anh = anchors[2 * aa + 1];
                float atlx = (float)ccx + 0.5f - anw * 0.5f;
                float atly = (float)ccy + 0.5f - anh * 0.5f;
                float ix = fminf(atlx + anw, g4.z) - fmaxf(atlx, g4.x);
                float iy = fminf(atly + anh, g4.w) - fmaxf(atly, g4.y);
                float inter = fmaxf(ix, 0.0f) * fmaxf(iy, 0.0f);
                float ov = inter * fastrcp(anw * anh + ga - inter);
                if (ov > best) { best = ov; ai = aa; aw = anw; ah = anh; }
            }
            skey[m] = valid ? (cell * A_N + ai) : -1;
            __builtin_amdgcn_s_waitcnt(0);      // LDS writes visible within wave

            // winner = last valid m holding its (cell,anchor) key (scan overwrite)
            bool winner = valid;
            if (valid) {
                int mykey = skey[m];
                for (int mm = m + 1; mm < M_N; ++mm)
                    if (skey[mm] == mykey) winner = false;
            }

            if (winner) {
                size_t obase = ((size_t)b * (A_N * CH_N) + (size_t)ai * CH_N) * HW_N + cell;
                float o0 = outputs[obase + 0 * HW_N];
                float o1 = outputs[obase + 1 * HW_N];
                float o2 = outputs[obase + 2 * HW_N];
                float o3 = outputs[obase + 3 * HW_N];
                float o4 = outputs[obase + 4 * HW_N];
                float sx = sigmoidf_(o0), sy = sigmoidf_(o1);
                float ew = __expf(o2), eh = __expf(o3);
                float conf = sigmoidf_(o4);
                float px = sx + (float)ccx, py = sy + (float)ccy;
                float pw = ew * aw, ph = eh * ah;
                float ptlx = px - pw * 0.5f, ptly = py - ph * 0.5f;
                float pbrx = px + pw * 0.5f, pbry = py + ph * 0.5f;
                float pa = pw * ph;

                float mi = 0.0f, maxdW = -1e30f;
                for (int mm = 0; mm < nobj; ++mm) {
                    float4 g = sg4[mm];
                    float gaM = (g.z - g.x) * (g.w - g.y);
                    float ix = fminf(pbrx, g.z) - fmaxf(ptlx, g.x);
                    float iy = fminf(pbry, g.w) - fmaxf(ptly, g.y);
                    float inter = fmaxf(ix, 0.0f) * fmaxf(iy, 0.0f);
                    mi = fmaxf(mi, inter * fastrcp(pa + gaM - inter));
                    maxdW = fmaxf(maxdW, fmaf(3.0f, inter, -(pa + gaM)));
                }

                float dcf = conf - mi;
                G = dcf * dcf;
                float bs = 2.0f - (pw / (float)W_N) * (ph / (float)H_N);
                float e0 = sx - (gx - (float)ccx);
                float e1 = sy - (gy - (float)ccy);
                float e2 = ew - sgw[m] / aw;
                float e3 = eh - sgh[m] / ah;
                G += bs * (e0 * e0 + e1 * e1 + e2 * e2 + e3 * e3);

                int cls = (int)sc[m];
                float mx = -1e30f, tv = 0.0f, logits[NCLS];
                #pragma unroll
                for (int c = 0; c < NCLS; ++c) {
                    logits[c] = outputs[obase + (size_t)(5 + c) * HW_N];
                    mx = fmaxf(mx, logits[c]);
                }
                float se = 0.0f;
                #pragma unroll
                for (int c = 0; c < NCLS; ++c) {
                    se += __expf(logits[c] - mx);
                    if (c == cls) tv = logits[c];
                }
                G += (mx + __logf(se)) - tv;

                c2A = conf * conf;
                c2H = (maxdW >= 0.0f) ? c2A : 0.0f;  // same algebra as noobj pass
            }
            // deterministic wave reduction (lane order fixed)
            #pragma unroll
            for (int off = 32; off > 0; off >>= 1) {
                G   += __shfl_down(G, off);
                c2A += __shfl_down(c2A, off);
                c2H += __shfl_down(c2H, off);
            }
            if (tid == 0) {
                Gb[b] = G; Asub[b] = c2A; Hsub[b] = c2H; nobjArr[b] = nobj;
            }
        }
    } else {
        // ---- noobj path: 2 consecutive locations per thread, float2 loads ----
        float locA = 0.0f, locH = 0.0f;
        bool any = false;
        if (tid < HALF_T) {
            int hw0 = half * HALF_LOC + tid * 2;
            size_t obase = ((size_t)b * (A_N * CH_N) + (size_t)a * CH_N) * HW_N;
            float2 O0 = *(const float2*)(outputs + obase + 0 * HW_N + hw0);
            float2 O1 = *(const float2*)(outputs + obase + 1 * HW_N + hw0);
            float2 O2 = *(const float2*)(outputs + obase + 2 * HW_N + hw0);
            float2 O3 = *(const float2*)(outputs + obase + 3 * HW_N + hw0);
            float2 O4 = *(const float2*)(outputs + obase + 4 * HW_N + hw0);
            float aw = anchors[2 * a], ah = anchors[2 * a + 1];

            int wy = hw0 / W_N;
            int wx = hw0 - wy * W_N;             // hw0 even, W even -> same row

            float sx0 = sigmoidf_(O0.x), sx1 = sigmoidf_(O0.y);
            float sy0 = sigmoidf_(O1.x), sy1 = sigmoidf_(O1.y);
            float pw0 = __expf(O2.x) * aw, pw1 = __expf(O2.y) * aw;
            float ph0 = __expf(O3.x) * ah, ph1 = __expf(O3.y) * ah;
            float px0 = sx0 + (float)wx, px1 = sx1 + (float)(wx + 1);
            float py0 = sy0 + (float)wy, py1 = sy1 + (float)wy;

            float ptlx0 = px0 - pw0 * 0.5f, ptly0 = py0 - ph0 * 0.5f;
            float pbrx0 = px0 + pw0 * 0.5f, pbry0 = py0 + ph0 * 0.5f;
            float ptlx1 = px1 - pw1 * 0.5f, ptly1 = py1 - ph1 * 0.5f;
            float pbrx1 = px1 + pw1 * 0.5f, pbry1 = py1 + ph1 * 0.5f;
            float pa0 = pw0 * ph0, pa1 = pw1 * ph1;

            // iou >= 0.5 <=> 3*inter - (pa+ga) >= 0 ; strict > for has_pos
            float maxd0 = -1e30f, maxd1 = -1e30f;
            #pragma unroll 2
            for (int m = 0; m < nobj; ++m) {
                float4 g = sg4[m];
                float ga = (g.z - g.x) * (g.w - g.y);
                float t0 = pa0 + ga, t1 = pa1 + ga;
                float ix0 = fminf(pbrx0, g.z) - fmaxf(ptlx0, g.x);
                float iy0 = fminf(pbry0, g.w) - fmaxf(ptly0, g.y);
                float in0 = fmaxf(ix0, 0.0f) * fmaxf(iy0, 0.0f);
                maxd0 = fmaxf(maxd0, fmaf(3.0f, in0, -t0));
                float ix1 = fminf(pbrx1, g.z) - fmaxf(ptlx1, g.x);
                float iy1 = fminf(pbry1, g.w) - fmaxf(ptly1, g.y);
                float in1 = fmaxf(ix1, 0.0f) * fmaxf(iy1, 0.0f);
                maxd1 = fmaxf(maxd1, fmaf(3.0f, in1, -t1));
            }
            float conf0 = sigmoidf_(O4.x), conf1 = sigmoidf_(O4.y);
            float c20 = conf0 * conf0, c21 = conf1 * conf1;
            locA = c20 + c21;
            locH = (maxd0 >= 0.0f ? c20 : 0.0f) + (maxd1 >= 0.0f ? c21 : 0.0f);
            any = (maxd0 > 0.0f) || (maxd1 > 0.0f);
        }

        int wany = __any(any) ? 1 : 0;
        #pragma unroll
        for (int off = 32; off > 0; off >>= 1) {
            locA += __shfl_down(locA, off);
            locH += __shfl_down(locH, off);
        }
        int wave = tid >> 6, lane = tid & 63;
        if (lane == 0) { rA[wave] = locA; rH[wave] = locH; rAny[wave] = wany; }
        __syncthreads();
        if (tid == 0) {
            A_part[nb] = rA[0] + rA[1] + rA[2];
            H_part[nb] = rH[0] + rH[1] + rH[2];
            any_part[nb] = rAny[0] | rAny[1] | rAny[2];
        }
    }
}

// ---------------------------------------------------------------------------
// Finish: 128 threads, one per batch; deterministic fixed-order reduction.
// ---------------------------------------------------------------------------
__global__ __launch_bounds__(128) void finish_kernel(
    const float* __restrict__ A_part, const float* __restrict__ H_part,
    const int* __restrict__ any_part,
    const float* __restrict__ Gb, const float* __restrict__ Asub,
    const float* __restrict__ Hsub, const int* __restrict__ nobjArr,
    float* __restrict__ out) {
    int t = threadIdx.x;  // == b
    float A = -Asub[t], Hs = -Hsub[t];
    int any = 0;
    #pragma unroll
    for (int j = 0; j < PARTS_PER_B; ++j) {
        A += A_part[t * PARTS_PER_B + j];
        Hs += H_part[t * PARTS_PER_B + j];
        any |= any_part[t * PARTS_PER_B + j];
    }
    float noobj = (nobjArr[t] > 0) ? (A - (any ? Hs : 0.0f)) : 0.0f;
    float v = Gb[t] + noobj;
    #pragma unroll
    for (int off = 32; off > 0; off >>= 1) v += __shfl_down(v, off);
    __shared__ float r[2];
    if ((t & 63) == 0) r[t >> 6] = v;
    __syncthreads();
    if (t == 0) out[0] = (r[0] + r[1]) / (float)B_N;
}

extern "C" void kernel_launch(void* const* d_in, const int* in_sizes, int n_in,
                              void* d_out, int out_size, void* d_ws, size_t ws_size,
                              hipStream_t stream) {
    const float* outputs = (const float*)d_in[0];
    const float* targets = (const float*)d_in[1];
    const float* anchors = (const float*)d_in[2];
    float* out = (float*)d_out;

    char* ws = (char*)d_ws;
    size_t off = 0;
    float* A_part = (float*)(ws + off); off += 4 * (size_t)NOOBJ_BLKS;
    float* H_part = (float*)(ws + off); off += 4 * (size_t)NOOBJ_BLKS;
    int* any_part = (int*)(ws + off);   off += 4 * (size_t)NOOBJ_BLKS;
    float* Gb = (float*)(ws + off);     off += 4 * B_N;
    float* Asub = (float*)(ws + off);   off += 4 * B_N;
    float* Hsub = (float*)(ws + off);   off += 4 * B_N;
    int* nobjArr = (int*)(ws + off);    off += 4 * B_N;
    // every slot above is unconditionally written each call -> no memset needed

    main_kernel<<<WIN_BLKS + NOOBJ_BLKS, BLK_T, 0, stream>>>(
        outputs, targets, anchors,
        A_part, H_part, any_part, Gb, Asub, Hsub, nobjArr);

    finish_kernel<<<1, 128, 0, stream>>>(A_part, H_part, any_part,
                                         Gb, Asub, Hsub, nobjArr, out);
}